// Round 4
// baseline (5190.463 us; speedup 1.0000x reference)
//
#include <hip/hip_runtime.h>
#include <hip/hip_bf16.h>
#include <math.h>

#define B_     128
#define L_     100
#define HID_   256
#define IND_   160
#define NCLASS 19
#define CAPD   16
#define NI     1600      // L_ * NUM_CAPS
#define OD     304       // NCLASS * CAPD
#define ENTITY 68

// ---------------------------------------------------------------------------
// Phase 0: embedding gather -> emb [b*L_+t][160]
// ---------------------------------------------------------------------------
__global__ void emb_gather(const int* __restrict__ word, const int* __restrict__ tag,
                           const int* __restrict__ pos1, const int* __restrict__ pos2,
                           const float* __restrict__ we, const float* __restrict__ te,
                           const float* __restrict__ p1e, const float* __restrict__ p2e,
                           float* __restrict__ emb)
{
    int idx = blockIdx.x * 256 + threadIdx.x;          // exactly B_*L_*IND_ threads
    int bt = idx / IND_;
    int k  = idx - bt * IND_;
    float v;
    if (k < 100)      v = we[word[bt] * 100 + k];
    else if (k < 120) v = te[tag[bt] * 20 + (k - 100)];
    else if (k < 140) v = p1e[pos1[bt] * 20 + (k - 120)];
    else              v = p2e[pos2[bt] * 20 + (k - 140)];
    emb[idx] = v;
}

// ---------------------------------------------------------------------------
// whh -> bf16 (halves the scan's per-step L2 weight stream)
// layout: [dir][g*256+j][k] bf16, row-major, same as fp32 source
// ---------------------------------------------------------------------------
__global__ void whh_to_bf16(const float* __restrict__ wf, const float* __restrict__ wb,
                            __hip_bfloat16* __restrict__ o)
{
    int idx = blockIdx.x * 256 + threadIdx.x;   // exactly 2*1024*256 threads
    const float* src = (idx < 262144) ? wf : wb;
    o[idx] = __float2bfloat16(src[idx & 262143]);
}

// ---------------------------------------------------------------------------
// Phase 1: input-gate GEMM.
// xg layout: [dir][t][bpair(64)][gj(1024)][2]  (b = bpair*2 + c)
// ---------------------------------------------------------------------------
__global__ void __launch_bounds__(256) gemm_xg(
    const float* __restrict__ emb,
    const float* __restrict__ wihf, const float* __restrict__ bihf, const float* __restrict__ bhhf,
    const float* __restrict__ wihb, const float* __restrict__ bihb, const float* __restrict__ bhhb,
    float* __restrict__ xg)
{
    int gt  = blockIdx.x;
    int t   = blockIdx.y;
    int dir = blockIdx.z;
    const float* w  = dir ? wihb : wihf;
    const float* bi = dir ? bihb : bihf;
    const float* bh = dir ? bhhb : bhhf;
    int gj0 = gt * 128;

    __shared__ float wsh[32][132];   // [k][gj], padded
    __shared__ float esh[32][132];   // [k][b],  padded

    int tid = threadIdx.x;
    int tx = tid & 15, ty = tid >> 4;

    float acc[8][8];
    #pragma unroll
    for (int i = 0; i < 8; ++i)
        #pragma unroll
        for (int j = 0; j < 8; ++j) acc[i][j] = 0.f;

    for (int k0 = 0; k0 < IND_; k0 += 32) {
        __syncthreads();
        #pragma unroll
        for (int m = 0; m < 16; ++m) {
            int e = m * 256 + tid;        // 0..4095
            int k = e & 31, g = e >> 5;   // g: row (gj or b)
            wsh[k][g] = w[(gj0 + g) * IND_ + k0 + k];
            esh[k][g] = emb[(g * L_ + t) * IND_ + k0 + k];
        }
        __syncthreads();
        #pragma unroll
        for (int k = 0; k < 32; ++k) {
            float wv[8], ev[8];
            #pragma unroll
            for (int q = 0; q < 8; ++q) wv[q] = wsh[k][ty * 8 + q];
            #pragma unroll
            for (int q = 0; q < 8; ++q) ev[q] = esh[k][tx * 8 + q];
            #pragma unroll
            for (int i = 0; i < 8; ++i)
                #pragma unroll
                for (int j = 0; j < 8; ++j) acc[i][j] = fmaf(wv[i], ev[j], acc[i][j]);
        }
    }
    #pragma unroll
    for (int i = 0; i < 8; ++i) {
        int gj = gj0 + ty * 8 + i;
        float bias = bi[gj] + bh[gj];
        #pragma unroll
        for (int j = 0; j < 8; ++j) {
            int b = tx * 8 + j;
            xg[((((size_t)dir * L_ + t) * 64 + (b >> 1)) * 1024 + gj) * 2 + (b & 1)]
                = acc[i][j] + bias;
        }
    }
}

// ---------------------------------------------------------------------------
// Phase 2: BiLSTM scan v4. Block = (dir, b-pair): 128 blocks x 512 threads.
// thread = (j = tid>>1, kc = tid&1); kc owns k in [kc*128, kc*128+128).
// bf16 weights streamed through a 2-deep register chunk buffer (8 chunks/step,
// prefetch 1 ahead ~400cyc compute covers L2 latency). h fp32 in LDS, double-
// buffered -> 1 barrier/step; [buf][b][k] layout = 2-way bank alias (free).
// 512-thr block => VGPR cap 256 (launch_bounds(512,2)) for prefetch depth.
// ---------------------------------------------------------------------------
__device__ __forceinline__ float sigm_f(float x) { return 1.f / (1.f + __expf(-x)); }
__device__ __forceinline__ float tanh_f(float x) {
    float e = __expf(-2.f * fabsf(x));        // in (0,1], never overflows
    float r = (1.f - e) / (1.f + e);
    return copysignf(r, x);
}

__global__ void __launch_bounds__(512, 2) lstm_scan_d(
    const float* __restrict__ xg, const __hip_bfloat16* __restrict__ wbf16,
    float* __restrict__ xf, float* __restrict__ xb)
{
    int blk = blockIdx.x;
    int dir = blk >> 6;            // 0..1
    int bp  = blk & 63;            // b-pair index
    int tid = threadIdx.x;
    int kc  = tid & 1;             // low lane bit
    int j   = tid >> 1;            // 0..255

    const unsigned short* wbase = (const unsigned short*)wbf16 + (size_t)dir * 262144;
    const uint4* wg[4];            // per-gate stream: uint4 = 8 bf16 = 8 consecutive k
    #pragma unroll
    for (int g = 0; g < 4; ++g)
        wg[g] = (const uint4*)(wbase + ((size_t)(g * HID_ + j) * HID_ + kc * 128));
    float* xo = dir ? xb : xf;

    __shared__ float hs[2][2][HID_];   // [buf][bsub][k]
    if (kc == 0) { hs[0][0][j] = 0.f; hs[0][1][j] = 0.f; }
    float c0 = 0.f, c1 = 0.f;
    __syncthreads();

    for (int t = 0; t < L_; ++t) {
        int slot = dir ? (L_ - 1 - t) : t;
        int buf = t & 1;
        // gate precompute loads (independent of h -> issue first)
        const float* xbase = xg + (((size_t)dir * L_ + slot) * 64 + bp) * 2048;
        float2 gp0 = *(const float2*)(xbase + (0 * HID_ + j) * 2);
        float2 gp1 = *(const float2*)(xbase + (1 * HID_ + j) * 2);
        float2 gp2 = *(const float2*)(xbase + (2 * HID_ + j) * 2);
        float2 gp3 = *(const float2*)(xbase + (3 * HID_ + j) * 2);

        const float4* hp0 = (const float4*)&hs[buf][0][kc * 128];
        const float4* hp1 = (const float4*)&hs[buf][1][kc * 128];

        float a00 = 0.f, a01 = 0.f, a10 = 0.f, a11 = 0.f;
        float a20 = 0.f, a21 = 0.f, a30 = 0.f, a31 = 0.f;

        uint4 wq[2][8];
        #pragma unroll
        for (int g = 0; g < 4; ++g) {
            wq[0][g * 2 + 0] = wg[g][0];
            wq[0][g * 2 + 1] = wg[g][1];
        }
        #pragma unroll
        for (int ch = 0; ch < 8; ++ch) {    // chunk = 16 k-values, all 4 gates
            int cur = ch & 1, nxt = cur ^ 1;
            if (ch < 7) {
                #pragma unroll
                for (int g = 0; g < 4; ++g) {
                    wq[nxt][g * 2 + 0] = wg[g][(ch + 1) * 2 + 0];
                    wq[nxt][g * 2 + 1] = wg[g][(ch + 1) * 2 + 1];
                }
            }
            float h0f[16], h1f[16];
            #pragma unroll
            for (int q = 0; q < 4; ++q) {
                float4 v0 = hp0[ch * 4 + q], v1 = hp1[ch * 4 + q];
                h0f[q*4+0] = v0.x; h0f[q*4+1] = v0.y; h0f[q*4+2] = v0.z; h0f[q*4+3] = v0.w;
                h1f[q*4+0] = v1.x; h1f[q*4+1] = v1.y; h1f[q*4+2] = v1.z; h1f[q*4+3] = v1.w;
            }
            #pragma unroll
            for (int m = 0; m < 2; ++m) {
                uint4 q0 = wq[cur][0 * 2 + m];
                uint4 q1 = wq[cur][1 * 2 + m];
                uint4 q2 = wq[cur][2 * 2 + m];
                uint4 q3 = wq[cur][3 * 2 + m];
                unsigned int u0[4] = {q0.x, q0.y, q0.z, q0.w};
                unsigned int u1[4] = {q1.x, q1.y, q1.z, q1.w};
                unsigned int u2[4] = {q2.x, q2.y, q2.z, q2.w};
                unsigned int u3[4] = {q3.x, q3.y, q3.z, q3.w};
                #pragma unroll
                for (int e = 0; e < 4; ++e) {
                    int k0 = m * 8 + e * 2;
                    float he0 = h0f[k0],     he1 = h1f[k0];
                    float ho0 = h0f[k0 + 1], ho1 = h1f[k0 + 1];
                    float w0l = __uint_as_float(u0[e] << 16);
                    float w0h = __uint_as_float(u0[e] & 0xffff0000u);
                    float w1l = __uint_as_float(u1[e] << 16);
                    float w1h = __uint_as_float(u1[e] & 0xffff0000u);
                    float w2l = __uint_as_float(u2[e] << 16);
                    float w2h = __uint_as_float(u2[e] & 0xffff0000u);
                    float w3l = __uint_as_float(u3[e] << 16);
                    float w3h = __uint_as_float(u3[e] & 0xffff0000u);
                    a00 = fmaf(w0l, he0, a00); a01 = fmaf(w0l, he1, a01);
                    a10 = fmaf(w1l, he0, a10); a11 = fmaf(w1l, he1, a11);
                    a20 = fmaf(w2l, he0, a20); a21 = fmaf(w2l, he1, a21);
                    a30 = fmaf(w3l, he0, a30); a31 = fmaf(w3l, he1, a31);
                    a00 = fmaf(w0h, ho0, a00); a01 = fmaf(w0h, ho1, a01);
                    a10 = fmaf(w1h, ho0, a10); a11 = fmaf(w1h, ho1, a11);
                    a20 = fmaf(w2h, ho0, a20); a21 = fmaf(w2h, ho1, a21);
                    a30 = fmaf(w3h, ho0, a30); a31 = fmaf(w3h, ho1, a31);
                }
            }
        }
        // reduce over the 2 kc lanes (lane xor 1, in-wave)
        a00 += __shfl_xor(a00, 1); a01 += __shfl_xor(a01, 1);
        a10 += __shfl_xor(a10, 1); a11 += __shfl_xor(a11, 1);
        a20 += __shfl_xor(a20, 1); a21 += __shfl_xor(a21, 1);
        a30 += __shfl_xor(a30, 1); a31 += __shfl_xor(a31, 1);

        a00 += gp0.x; a01 += gp0.y; a10 += gp1.x; a11 += gp1.y;
        a20 += gp2.x; a21 += gp2.y; a30 += gp3.x; a31 += gp3.y;

        float i0 = sigm_f(a00), f0 = sigm_f(a10), g0 = tanh_f(a20), o0 = sigm_f(a30);
        c0 = f0 * c0 + i0 * g0;
        float h0 = o0 * tanh_f(c0);
        float i1 = sigm_f(a01), f1 = sigm_f(a11), g1 = tanh_f(a21), o1 = sigm_f(a31);
        c1 = f1 * c1 + i1 * g1;
        float h1 = o1 * tanh_f(c1);

        if (kc == 0) {
            int nbuf = buf ^ 1;
            hs[nbuf][0][j] = h0; hs[nbuf][1][j] = h1;
            // block-local contiguous layout: [slot][bp][j][2] -> no write amplification
            float* xp = xo + (((size_t)slot * 64 + bp) * HID_ + j) * 2;
            xp[0] = h0; xp[1] = h1;
        }
        __syncthreads();
    }
}

// x[l][j][b] = xf + xb  (inputs in scan-local layout [l][bp][j][2])
__global__ void x_add(const float* __restrict__ xf, const float* __restrict__ xb,
                      float* __restrict__ x)
{
    int idx = blockIdx.x * 256 + threadIdx.x;   // exactly L_*HID_*B_ threads
    int b = idx & 127;
    int r = idx >> 7;
    int j = r & 255;
    int l = r >> 8;
    int src = ((l * 64 + (b >> 1)) * HID_ + j) * 2 + (b & 1);
    x[idx] = xf[src] + xb[src];
}

// ---------------------------------------------------------------------------
// Phase 3: entity features, attention, primary capsules
// ---------------------------------------------------------------------------
__global__ void find_entity(const int* __restrict__ pos1, const int* __restrict__ pos2,
                            int* __restrict__ e)
{
    int b = threadIdx.x;
    int e1 = 0, e2 = 0;
    for (int l = L_ - 1; l >= 0; --l) if (pos1[b * L_ + l] == ENTITY) e1 = l;
    for (int l = L_ - 1; l >= 0; --l) if (pos2[b * L_ + l] == ENTITY) e2 = l;
    e[b] = e1; e[B_ + b] = e2;
}

__global__ void compute_he(const float* __restrict__ x, const int* __restrict__ e,
                           float* __restrict__ he)
{
    int j = blockIdx.x, b = threadIdx.x;
    int e1 = e[b], e2 = e[B_ + b];
    he[j * B_ + b] = x[((size_t)e1 * HID_ + j) * B_ + b] + x[((size_t)e2 * HID_ + j) * B_ + b];
}

__global__ void att_logits(const float* __restrict__ x, const float* __restrict__ he,
                           float* __restrict__ logits)
{
    int l = blockIdx.x, b = threadIdx.x;
    float acc = 0.f;
    for (int j = 0; j < HID_; ++j)
        acc = fmaf(x[((size_t)l * HID_ + j) * B_ + b], he[j * B_ + b], acc);
    logits[l * B_ + b] = acc;
}

__global__ void att_softmax(const float* __restrict__ logits, float* __restrict__ att)
{
    int b = threadIdx.x;
    float m = -1e30f;
    for (int l = 0; l < L_; ++l) m = fmaxf(m, logits[l * B_ + b]);
    float s = 0.f;
    for (int l = 0; l < L_; ++l) s += expf(logits[l * B_ + b] - m);
    float inv = 1.f / s;
    for (int l = 0; l < L_; ++l) att[l * B_ + b] = expf(logits[l * B_ + b] - m) * inv;
}

// primary capsules: u[i][b][c], squashed
__global__ void u_squash(const float* __restrict__ x, float* __restrict__ u)
{
    int i = blockIdx.x, b = threadIdx.x;
    int l = i >> 4, cap = i & 15;
    float vals[16]; float n2 = 0.f;
    #pragma unroll
    for (int c2 = 0; c2 < 16; ++c2) {
        float v = x[((size_t)l * HID_ + cap * 16 + c2) * B_ + b];
        vals[c2] = v; n2 = fmaf(v, v, n2);
    }
    float f = (n2 / (1.f + n2)) / sqrtf(n2 + 1e-9f);
    #pragma unroll
    for (int c2 = 0; c2 < 16; ++c2)
        u[((size_t)i * B_ + b) * 16 + c2] = vals[c2] * f;
}

// ---------------------------------------------------------------------------
// Phase 4: routing
// ---------------------------------------------------------------------------
__global__ void bb_init(const float* __restrict__ br, float* __restrict__ bb)
{
    int idx = blockIdx.x * 256 + threadIdx.x;   // exactly B_*NI*NCLASS threads
    bb[idx] = br[idx % (NI * NCLASS)];
}

__global__ void __launch_bounds__(320) s_pass(
    const float* __restrict__ u, const float* __restrict__ W,
    const float* __restrict__ bb, const float* __restrict__ att,
    float* __restrict__ partial)
{
    int ic = blockIdx.x, bt = blockIdx.y;
    int i0 = ic * 16, b0 = bt * 16;
    __shared__ float C[16][16][20];   // [bl][il][o], padded
    int tid = threadIdx.x;
    if (tid < 256) {
        int bl = tid >> 4, il = tid & 15;
        int b = b0 + bl, i = i0 + il;
        const float* bbp = bb + ((size_t)b * NI + i) * NCLASS;
        float m = bbp[0];
        #pragma unroll
        for (int o = 1; o < NCLASS; ++o) m = fmaxf(m, bbp[o]);
        float s = 0.f; float e[NCLASS];
        #pragma unroll
        for (int o = 0; o < NCLASS; ++o) { e[o] = expf(bbp[o] - m); s += e[o]; }
        float al = att[(i >> 4) * B_ + b] / s;
        #pragma unroll
        for (int o = 0; o < NCLASS; ++o) C[bl][il][o] = e[o] * al;
    }
    __syncthreads();
    if (tid >= OD) return;
    int od = tid, o = od >> 4;
    float acc[16];
    #pragma unroll
    for (int bl = 0; bl < 16; ++bl) acc[bl] = 0.f;
    for (int il = 0; il < 16; ++il) {
        int i = i0 + il;
        const float* wp = W + (size_t)i * 16 * OD + od;
        float w[16];
        #pragma unroll
        for (int c2 = 0; c2 < 16; ++c2) w[c2] = wp[c2 * OD];     // coalesced over od
        const float* up = u + ((size_t)i * B_ + b0) * 16;        // uniform -> s_load
        #pragma unroll
        for (int bl = 0; bl < 16; ++bl) {
            float uh = 0.f;
            #pragma unroll
            for (int c2 = 0; c2 < 16; ++c2) uh = fmaf(up[bl * 16 + c2], w[c2], uh);
            acc[bl] = fmaf(C[bl][il][o], uh, acc[bl]);
        }
    }
    #pragma unroll
    for (int bl = 0; bl < 16; ++bl)
        partial[((size_t)ic * B_ + b0 + bl) * OD + od] = acc[bl];
}

__global__ void s_reduce(const float* __restrict__ partial, float* __restrict__ s)
{
    int idx = blockIdx.x * 256 + threadIdx.x;   // exactly B_*OD threads
    int b = idx / OD, od = idx - b * OD;
    float acc = 0.f;
    for (int ic = 0; ic < 100; ++ic) acc += partial[((size_t)ic * B_ + b) * OD + od];
    s[idx] = acc;
}

__global__ void squash_v(const float* __restrict__ s, float* __restrict__ v,
                         float* __restrict__ out, int write_out)
{
    int idx = blockIdx.x * 256 + threadIdx.x;
    if (idx >= B_ * NCLASS) return;
    const float* sp = s + (size_t)idx * 16;     // b*304 + o*16 == idx*16
    float vals[16]; float n2 = 0.f;
    #pragma unroll
    for (int d = 0; d < 16; ++d) { vals[d] = sp[d]; n2 = fmaf(vals[d], vals[d], n2); }
    float f = (n2 / (1.f + n2)) / sqrtf(n2 + 1e-9f);
    float n2v = 0.f;
    #pragma unroll
    for (int d = 0; d < 16; ++d) {
        float vv = vals[d] * f;
        v[(size_t)idx * 16 + d] = vv;
        n2v = fmaf(vv, vv, n2v);
    }
    if (write_out) out[idx] = sqrtf(n2v + 1e-9f);
}

__global__ void __launch_bounds__(320) bb_pass(
    const float* __restrict__ u, const float* __restrict__ W,
    const float* __restrict__ v, float* __restrict__ bb)
{
    int ic = blockIdx.x, bt = blockIdx.y;
    int i0 = ic * 16, b0 = bt * 16;
    int tid = threadIdx.x;
    if (tid >= OD) return;
    int od = tid, o = od >> 4, d = od & 15;
    float vv[16];
    #pragma unroll
    for (int bl = 0; bl < 16; ++bl) vv[bl] = v[(size_t)(b0 + bl) * OD + od];
    for (int il = 0; il < 16; ++il) {
        int i = i0 + il;
        const float* wp = W + (size_t)i * 16 * OD + od;
        float w[16];
        #pragma unroll
        for (int c2 = 0; c2 < 16; ++c2) w[c2] = wp[c2 * OD];
        const float* up = u + ((size_t)i * B_ + b0) * 16;
        #pragma unroll
        for (int bl = 0; bl < 16; ++bl) {
            float uh = 0.f;
            #pragma unroll
            for (int c2 = 0; c2 < 16; ++c2) uh = fmaf(up[bl * 16 + c2], w[c2], uh);
            float p = uh * vv[bl];
            p += __shfl_xor(p, 1);
            p += __shfl_xor(p, 2);
            p += __shfl_xor(p, 4);
            p += __shfl_xor(p, 8);
            if (d == 0) bb[((size_t)(b0 + bl) * NI + i) * NCLASS + o] += p;
        }
    }
}

// ---------------------------------------------------------------------------
extern "C" void kernel_launch(void* const* d_in, const int* in_sizes, int n_in,
                              void* d_out, int out_size, void* d_ws, size_t ws_size,
                              hipStream_t stream)
{
    (void)in_sizes; (void)n_in; (void)out_size; (void)ws_size;
    const int*   word = (const int*)d_in[0];
    const int*   tag  = (const int*)d_in[1];
    const int*   pos1 = (const int*)d_in[2];
    const int*   pos2 = (const int*)d_in[3];
    const float* we   = (const float*)d_in[4];
    const float* te   = (const float*)d_in[5];
    const float* p1e  = (const float*)d_in[6];
    const float* p2e  = (const float*)d_in[7];
    const float* wihf = (const float*)d_in[8];
    const float* whhf = (const float*)d_in[9];
    const float* bihf = (const float*)d_in[10];
    const float* bhhf = (const float*)d_in[11];
    const float* wihb = (const float*)d_in[12];
    const float* whhb = (const float*)d_in[13];
    const float* bihb = (const float*)d_in[14];
    const float* bhhb = (const float*)d_in[15];
    const float* Wc   = (const float*)d_in[16];
    const float* br   = (const float*)d_in[17];

    float* wsp    = (float*)d_ws;
    float* emb    = wsp;                       //  2,048,000
    float* xg     = wsp + 2048000;             // 26,214,400
    float* xf     = xg + 26214400;             //  3,276,800
    float* xb     = xf + 3276800;              //  3,276,800
    float* he     = xb + 3276800;              //     32,768
    float* logits = he + 32768;                //     12,800
    float* att    = logits + 12800;            //     12,800
    int*   e      = (int*)(att + 12800);       //        256 ints
    __hip_bfloat16* wbf = (__hip_bfloat16*)(att + 12800 + 256);  // 524,288 bf16
    // post-scan buffers alias the (dead-after-scan) xg region
    float* x    = xg;                          //  3,276,800
    float* u    = xg + 3276800;                //  3,276,800
    float* bb   = xg + 6553600;                //  3,891,200
    float* part = xg + 10444800;               //  3,891,200
    float* s    = xg + 14336000;               //     38,912
    float* v    = s + 38912;                   //     38,912
    float* out  = (float*)d_out;

    emb_gather<<<8000, 256, 0, stream>>>(word, tag, pos1, pos2, we, te, p1e, p2e, emb);
    whh_to_bf16<<<2048, 256, 0, stream>>>(whhf, whhb, wbf);
    gemm_xg<<<dim3(8, 100, 2), 256, 0, stream>>>(emb, wihf, bihf, bhhf, wihb, bihb, bhhb, xg);
    lstm_scan_d<<<128, 512, 0, stream>>>(xg, wbf, xf, xb);
    x_add<<<12800, 256, 0, stream>>>(xf, xb, x);
    find_entity<<<1, 128, 0, stream>>>(pos1, pos2, e);
    compute_he<<<256, 128, 0, stream>>>(x, e, he);
    att_logits<<<100, 128, 0, stream>>>(x, he, logits);
    att_softmax<<<1, 128, 0, stream>>>(logits, att);
    u_squash<<<1600, 128, 0, stream>>>(x, u);
    bb_init<<<15200, 256, 0, stream>>>(br, bb);
    for (int it = 0; it < 3; ++it) {
        s_pass<<<dim3(100, 8), 320, 0, stream>>>(u, Wc, bb, att, part);
        s_reduce<<<152, 256, 0, stream>>>(part, s);
        squash_v<<<10, 256, 0, stream>>>(s, v, out, (it == 2) ? 1 : 0);
        if (it < 2) bb_pass<<<dim3(100, 8), 320, 0, stream>>>(u, Wc, v, bb);
    }
}

// Round 5
// 4818.686 us; speedup vs baseline: 1.0772x; 1.0772x over previous
//
#include <hip/hip_runtime.h>
#include <math.h>

#define B_     128
#define L_     100
#define HID_   256
#define IND_   160
#define NCLASS 19
#define CAPD   16
#define NI     1600      // L_ * NUM_CAPS
#define OD     304       // NCLASS * CAPD
#define ENTITY 68

// ---------------------------------------------------------------------------
// Phase 0: embedding gather -> emb [b*L_+t][160]
// ---------------------------------------------------------------------------
__global__ void emb_gather(const int* __restrict__ word, const int* __restrict__ tag,
                           const int* __restrict__ pos1, const int* __restrict__ pos2,
                           const float* __restrict__ we, const float* __restrict__ te,
                           const float* __restrict__ p1e, const float* __restrict__ p2e,
                           float* __restrict__ emb)
{
    int idx = blockIdx.x * 256 + threadIdx.x;          // exactly B_*L_*IND_ threads
    int bt = idx / IND_;
    int k  = idx - bt * IND_;
    float v;
    if (k < 100)      v = we[word[bt] * 100 + k];
    else if (k < 120) v = te[tag[bt] * 20 + (k - 100)];
    else if (k < 140) v = p1e[pos1[bt] * 20 + (k - 120)];
    else              v = p2e[pos2[bt] * 20 + (k - 140)];
    emb[idx] = v;
}

// ---------------------------------------------------------------------------
// Phase 1: input-gate GEMM.
// xg layout: [dir][t][bpair(64)][gj(1024)][2]  (b = bpair*2 + c)
// ---------------------------------------------------------------------------
__global__ void __launch_bounds__(256) gemm_xg(
    const float* __restrict__ emb,
    const float* __restrict__ wihf, const float* __restrict__ bihf, const float* __restrict__ bhhf,
    const float* __restrict__ wihb, const float* __restrict__ bihb, const float* __restrict__ bhhb,
    float* __restrict__ xg)
{
    int gt  = blockIdx.x;
    int t   = blockIdx.y;
    int dir = blockIdx.z;
    const float* w  = dir ? wihb : wihf;
    const float* bi = dir ? bihb : bihf;
    const float* bh = dir ? bhhb : bhhf;
    int gj0 = gt * 128;

    __shared__ float wsh[32][132];   // [k][gj], padded
    __shared__ float esh[32][132];   // [k][b],  padded

    int tid = threadIdx.x;
    int tx = tid & 15, ty = tid >> 4;

    float acc[8][8];
    #pragma unroll
    for (int i = 0; i < 8; ++i)
        #pragma unroll
        for (int j = 0; j < 8; ++j) acc[i][j] = 0.f;

    for (int k0 = 0; k0 < IND_; k0 += 32) {
        __syncthreads();
        #pragma unroll
        for (int m = 0; m < 16; ++m) {
            int e = m * 256 + tid;        // 0..4095
            int k = e & 31, g = e >> 5;   // g: row (gj or b)
            wsh[k][g] = w[(gj0 + g) * IND_ + k0 + k];
            esh[k][g] = emb[(g * L_ + t) * IND_ + k0 + k];
        }
        __syncthreads();
        #pragma unroll
        for (int k = 0; k < 32; ++k) {
            float wv[8], ev[8];
            #pragma unroll
            for (int q = 0; q < 8; ++q) wv[q] = wsh[k][ty * 8 + q];
            #pragma unroll
            for (int q = 0; q < 8; ++q) ev[q] = esh[k][tx * 8 + q];
            #pragma unroll
            for (int i = 0; i < 8; ++i)
                #pragma unroll
                for (int j = 0; j < 8; ++j) acc[i][j] = fmaf(wv[i], ev[j], acc[i][j]);
        }
    }
    #pragma unroll
    for (int i = 0; i < 8; ++i) {
        int gj = gj0 + ty * 8 + i;
        float bias = bi[gj] + bh[gj];
        #pragma unroll
        for (int j = 0; j < 8; ++j) {
            int b = tx * 8 + j;
            xg[((((size_t)dir * L_ + t) * 64 + (b >> 1)) * 1024 + gj) * 2 + (b & 1)]
                = acc[i][j] + bias;
        }
    }
}

// ---------------------------------------------------------------------------
// Phase 2: BiLSTM scan v5. Block = (dir, b-pair): 128 blocks x 512 threads.
// thread = (j = tid>>1, kc = tid&1); kc owns k in [kc*128, kc*128+128).
// fp32 weights read DIRECTLY from d_in (empirically L2-resident: R1-R3 FETCH
// ~59MB vs R4's ws-staged bf16 at 6.15GB = zero reuse). Register double-
// buffered chunks (8 chunks of 16 k, 1-ahead prefetch, 128 VGPR in flight)
// fix R3's dependent-load latency binding. h fp32 in LDS, double-buffered ->
// 1 barrier/step. Model: L2-BW 3.5us/step + VALU 1.7us/step -> ~400-500us.
// ---------------------------------------------------------------------------
__device__ __forceinline__ float sigm_f(float x) { return 1.f / (1.f + __expf(-x)); }
__device__ __forceinline__ float tanh_f(float x) {
    float e = __expf(-2.f * fabsf(x));        // in (0,1], never overflows
    float r = (1.f - e) / (1.f + e);
    return copysignf(r, x);
}

__global__ void __launch_bounds__(512, 2) lstm_scan_e(
    const float* __restrict__ xg,
    const float* __restrict__ whhf, const float* __restrict__ whhb,
    float* __restrict__ xf, float* __restrict__ xb)
{
    int blk = blockIdx.x;
    int dir = blk >> 6;            // 0..1
    int bp  = blk & 63;            // b-pair index
    int tid = threadIdx.x;
    int kc  = tid & 1;             // low lane bit
    int j   = tid >> 1;            // 0..255

    const float* whh = dir ? whhb : whhf;
    const float4* wg[4];           // per-gate k-stream (kc half: 128 k = 32 float4)
    #pragma unroll
    for (int g = 0; g < 4; ++g)
        wg[g] = (const float4*)(whh + (size_t)(g * HID_ + j) * HID_ + kc * 128);
    float* xo = dir ? xb : xf;

    __shared__ float hs[2][2][HID_];   // [buf][bsub][k]
    if (kc == 0) { hs[0][0][j] = 0.f; hs[0][1][j] = 0.f; }
    float c0 = 0.f, c1 = 0.f;
    __syncthreads();

    for (int t = 0; t < L_; ++t) {
        int slot = dir ? (L_ - 1 - t) : t;
        int buf = t & 1;
        // gate precompute loads (independent of h -> issue first)
        const float* xbase = xg + (((size_t)dir * L_ + slot) * 64 + bp) * 2048;
        float2 gp0 = *(const float2*)(xbase + (0 * HID_ + j) * 2);
        float2 gp1 = *(const float2*)(xbase + (1 * HID_ + j) * 2);
        float2 gp2 = *(const float2*)(xbase + (2 * HID_ + j) * 2);
        float2 gp3 = *(const float2*)(xbase + (3 * HID_ + j) * 2);

        const float4* hp0 = (const float4*)&hs[buf][0][kc * 128];
        const float4* hp1 = (const float4*)&hs[buf][1][kc * 128];

        float a00 = 0.f, a01 = 0.f, a10 = 0.f, a11 = 0.f;
        float a20 = 0.f, a21 = 0.f, a30 = 0.f, a31 = 0.f;

        // chunk = 16 k-values (4 float4/gate), double-buffered in registers
        float4 wq[2][4][4];   // [buf][gate][q]
        #pragma unroll
        for (int g = 0; g < 4; ++g)
            #pragma unroll
            for (int q = 0; q < 4; ++q) wq[0][g][q] = wg[g][q];

        #pragma unroll
        for (int ch = 0; ch < 8; ++ch) {
            int cur = ch & 1, nxt = cur ^ 1;
            if (ch < 7) {
                #pragma unroll
                for (int g = 0; g < 4; ++g)
                    #pragma unroll
                    for (int q = 0; q < 4; ++q) wq[nxt][g][q] = wg[g][(ch + 1) * 4 + q];
            }
            float4 h0q[4], h1q[4];
            #pragma unroll
            for (int q = 0; q < 4; ++q) { h0q[q] = hp0[ch * 4 + q]; h1q[q] = hp1[ch * 4 + q]; }
            #pragma unroll
            for (int q = 0; q < 4; ++q) {
                float4 w0 = wq[cur][0][q], w1 = wq[cur][1][q];
                float4 w2 = wq[cur][2][q], w3 = wq[cur][3][q];
                float4 hA = h0q[q], hB = h1q[q];
                a00 = fmaf(w0.x, hA.x, a00); a01 = fmaf(w0.x, hB.x, a01);
                a10 = fmaf(w1.x, hA.x, a10); a11 = fmaf(w1.x, hB.x, a11);
                a20 = fmaf(w2.x, hA.x, a20); a21 = fmaf(w2.x, hB.x, a21);
                a30 = fmaf(w3.x, hA.x, a30); a31 = fmaf(w3.x, hB.x, a31);
                a00 = fmaf(w0.y, hA.y, a00); a01 = fmaf(w0.y, hB.y, a01);
                a10 = fmaf(w1.y, hA.y, a10); a11 = fmaf(w1.y, hB.y, a11);
                a20 = fmaf(w2.y, hA.y, a20); a21 = fmaf(w2.y, hB.y, a21);
                a30 = fmaf(w3.y, hA.y, a30); a31 = fmaf(w3.y, hB.y, a31);
                a00 = fmaf(w0.z, hA.z, a00); a01 = fmaf(w0.z, hB.z, a01);
                a10 = fmaf(w1.z, hA.z, a10); a11 = fmaf(w1.z, hB.z, a11);
                a20 = fmaf(w2.z, hA.z, a20); a21 = fmaf(w2.z, hB.z, a21);
                a30 = fmaf(w3.z, hA.z, a30); a31 = fmaf(w3.z, hB.z, a31);
                a00 = fmaf(w0.w, hA.w, a00); a01 = fmaf(w0.w, hB.w, a01);
                a10 = fmaf(w1.w, hA.w, a10); a11 = fmaf(w1.w, hB.w, a11);
                a20 = fmaf(w2.w, hA.w, a20); a21 = fmaf(w2.w, hB.w, a21);
                a30 = fmaf(w3.w, hA.w, a30); a31 = fmaf(w3.w, hB.w, a31);
            }
        }
        // reduce over the 2 kc lanes (lane xor 1, in-wave)
        a00 += __shfl_xor(a00, 1); a01 += __shfl_xor(a01, 1);
        a10 += __shfl_xor(a10, 1); a11 += __shfl_xor(a11, 1);
        a20 += __shfl_xor(a20, 1); a21 += __shfl_xor(a21, 1);
        a30 += __shfl_xor(a30, 1); a31 += __shfl_xor(a31, 1);

        a00 += gp0.x; a01 += gp0.y; a10 += gp1.x; a11 += gp1.y;
        a20 += gp2.x; a21 += gp2.y; a30 += gp3.x; a31 += gp3.y;

        float i0 = sigm_f(a00), f0 = sigm_f(a10), g0 = tanh_f(a20), o0 = sigm_f(a30);
        c0 = f0 * c0 + i0 * g0;
        float h0 = o0 * tanh_f(c0);
        float i1 = sigm_f(a01), f1 = sigm_f(a11), g1 = tanh_f(a21), o1 = sigm_f(a31);
        c1 = f1 * c1 + i1 * g1;
        float h1 = o1 * tanh_f(c1);

        if (kc == 0) {
            int nbuf = buf ^ 1;
            hs[nbuf][0][j] = h0; hs[nbuf][1][j] = h1;
            // block-local contiguous layout: [slot][bp][j][2] -> no write amplification
            float* xp = xo + (((size_t)slot * 64 + bp) * HID_ + j) * 2;
            xp[0] = h0; xp[1] = h1;
        }
        __syncthreads();
    }
}

// x[l][j][b] = xf + xb  (inputs in scan-local layout [l][bp][j][2])
__global__ void x_add(const float* __restrict__ xf, const float* __restrict__ xb,
                      float* __restrict__ x)
{
    int idx = blockIdx.x * 256 + threadIdx.x;   // exactly L_*HID_*B_ threads
    int b = idx & 127;
    int r = idx >> 7;
    int j = r & 255;
    int l = r >> 8;
    int src = ((l * 64 + (b >> 1)) * HID_ + j) * 2 + (b & 1);
    x[idx] = xf[src] + xb[src];
}

// ---------------------------------------------------------------------------
// Phase 3: entity features, attention, primary capsules
// ---------------------------------------------------------------------------
__global__ void find_entity(const int* __restrict__ pos1, const int* __restrict__ pos2,
                            int* __restrict__ e)
{
    int b = threadIdx.x;
    int e1 = 0, e2 = 0;
    for (int l = L_ - 1; l >= 0; --l) if (pos1[b * L_ + l] == ENTITY) e1 = l;
    for (int l = L_ - 1; l >= 0; --l) if (pos2[b * L_ + l] == ENTITY) e2 = l;
    e[b] = e1; e[B_ + b] = e2;
}

__global__ void compute_he(const float* __restrict__ x, const int* __restrict__ e,
                           float* __restrict__ he)
{
    int j = blockIdx.x, b = threadIdx.x;
    int e1 = e[b], e2 = e[B_ + b];
    he[j * B_ + b] = x[((size_t)e1 * HID_ + j) * B_ + b] + x[((size_t)e2 * HID_ + j) * B_ + b];
}

__global__ void att_logits(const float* __restrict__ x, const float* __restrict__ he,
                           float* __restrict__ logits)
{
    int l = blockIdx.x, b = threadIdx.x;
    float acc = 0.f;
    for (int j = 0; j < HID_; ++j)
        acc = fmaf(x[((size_t)l * HID_ + j) * B_ + b], he[j * B_ + b], acc);
    logits[l * B_ + b] = acc;
}

__global__ void att_softmax(const float* __restrict__ logits, float* __restrict__ att)
{
    int b = threadIdx.x;
    float m = -1e30f;
    for (int l = 0; l < L_; ++l) m = fmaxf(m, logits[l * B_ + b]);
    float s = 0.f;
    for (int l = 0; l < L_; ++l) s += expf(logits[l * B_ + b] - m);
    float inv = 1.f / s;
    for (int l = 0; l < L_; ++l) att[l * B_ + b] = expf(logits[l * B_ + b] - m) * inv;
}

// primary capsules: u[i][b][c], squashed
__global__ void u_squash(const float* __restrict__ x, float* __restrict__ u)
{
    int i = blockIdx.x, b = threadIdx.x;
    int l = i >> 4, cap = i & 15;
    float vals[16]; float n2 = 0.f;
    #pragma unroll
    for (int c2 = 0; c2 < 16; ++c2) {
        float v = x[((size_t)l * HID_ + cap * 16 + c2) * B_ + b];
        vals[c2] = v; n2 = fmaf(v, v, n2);
    }
    float f = (n2 / (1.f + n2)) / sqrtf(n2 + 1e-9f);
    #pragma unroll
    for (int c2 = 0; c2 < 16; ++c2)
        u[((size_t)i * B_ + b) * 16 + c2] = vals[c2] * f;
}

// ---------------------------------------------------------------------------
// Phase 4: routing
// ---------------------------------------------------------------------------
__global__ void bb_init(const float* __restrict__ br, float* __restrict__ bb)
{
    int idx = blockIdx.x * 256 + threadIdx.x;   // exactly B_*NI*NCLASS threads
    bb[idx] = br[idx % (NI * NCLASS)];
}

__global__ void __launch_bounds__(320) s_pass(
    const float* __restrict__ u, const float* __restrict__ W,
    const float* __restrict__ bb, const float* __restrict__ att,
    float* __restrict__ partial)
{
    int ic = blockIdx.x, bt = blockIdx.y;
    int i0 = ic * 16, b0 = bt * 16;
    __shared__ float C[16][16][20];   // [bl][il][o], padded
    int tid = threadIdx.x;
    if (tid < 256) {
        int bl = tid >> 4, il = tid & 15;
        int b = b0 + bl, i = i0 + il;
        const float* bbp = bb + ((size_t)b * NI + i) * NCLASS;
        float m = bbp[0];
        #pragma unroll
        for (int o = 1; o < NCLASS; ++o) m = fmaxf(m, bbp[o]);
        float s = 0.f; float e[NCLASS];
        #pragma unroll
        for (int o = 0; o < NCLASS; ++o) { e[o] = expf(bbp[o] - m); s += e[o]; }
        float al = att[(i >> 4) * B_ + b] / s;
        #pragma unroll
        for (int o = 0; o < NCLASS; ++o) C[bl][il][o] = e[o] * al;
    }
    __syncthreads();
    if (tid >= OD) return;
    int od = tid, o = od >> 4;
    float acc[16];
    #pragma unroll
    for (int bl = 0; bl < 16; ++bl) acc[bl] = 0.f;
    for (int il = 0; il < 16; ++il) {
        int i = i0 + il;
        const float* wp = W + (size_t)i * 16 * OD + od;
        float w[16];
        #pragma unroll
        for (int c2 = 0; c2 < 16; ++c2) w[c2] = wp[c2 * OD];     // coalesced over od
        const float* up = u + ((size_t)i * B_ + b0) * 16;        // uniform -> s_load
        #pragma unroll
        for (int bl = 0; bl < 16; ++bl) {
            float uh = 0.f;
            #pragma unroll
            for (int c2 = 0; c2 < 16; ++c2) uh = fmaf(up[bl * 16 + c2], w[c2], uh);
            acc[bl] = fmaf(C[bl][il][o], uh, acc[bl]);
        }
    }
    #pragma unroll
    for (int bl = 0; bl < 16; ++bl)
        partial[((size_t)ic * B_ + b0 + bl) * OD + od] = acc[bl];
}

__global__ void s_reduce(const float* __restrict__ partial, float* __restrict__ s)
{
    int idx = blockIdx.x * 256 + threadIdx.x;   // exactly B_*OD threads
    int b = idx / OD, od = idx - b * OD;
    float acc = 0.f;
    for (int ic = 0; ic < 100; ++ic) acc += partial[((size_t)ic * B_ + b) * OD + od];
    s[idx] = acc;
}

__global__ void squash_v(const float* __restrict__ s, float* __restrict__ v,
                         float* __restrict__ out, int write_out)
{
    int idx = blockIdx.x * 256 + threadIdx.x;
    if (idx >= B_ * NCLASS) return;
    const float* sp = s + (size_t)idx * 16;     // b*304 + o*16 == idx*16
    float vals[16]; float n2 = 0.f;
    #pragma unroll
    for (int d = 0; d < 16; ++d) { vals[d] = sp[d]; n2 = fmaf(vals[d], vals[d], n2); }
    float f = (n2 / (1.f + n2)) / sqrtf(n2 + 1e-9f);
    float n2v = 0.f;
    #pragma unroll
    for (int d = 0; d < 16; ++d) {
        float vv = vals[d] * f;
        v[(size_t)idx * 16 + d] = vv;
        n2v = fmaf(vv, vv, n2v);
    }
    if (write_out) out[idx] = sqrtf(n2v + 1e-9f);
}

__global__ void __launch_bounds__(320) bb_pass(
    const float* __restrict__ u, const float* __restrict__ W,
    const float* __restrict__ v, float* __restrict__ bb)
{
    int ic = blockIdx.x, bt = blockIdx.y;
    int i0 = ic * 16, b0 = bt * 16;
    int tid = threadIdx.x;
    if (tid >= OD) return;
    int od = tid, o = od >> 4, d = od & 15;
    float vv[16];
    #pragma unroll
    for (int bl = 0; bl < 16; ++bl) vv[bl] = v[(size_t)(b0 + bl) * OD + od];
    for (int il = 0; il < 16; ++il) {
        int i = i0 + il;
        const float* wp = W + (size_t)i * 16 * OD + od;
        float w[16];
        #pragma unroll
        for (int c2 = 0; c2 < 16; ++c2) w[c2] = wp[c2 * OD];
        const float* up = u + ((size_t)i * B_ + b0) * 16;
        #pragma unroll
        for (int bl = 0; bl < 16; ++bl) {
            float uh = 0.f;
            #pragma unroll
            for (int c2 = 0; c2 < 16; ++c2) uh = fmaf(up[bl * 16 + c2], w[c2], uh);
            float p = uh * vv[bl];
            p += __shfl_xor(p, 1);
            p += __shfl_xor(p, 2);
            p += __shfl_xor(p, 4);
            p += __shfl_xor(p, 8);
            if (d == 0) bb[((size_t)(b0 + bl) * NI + i) * NCLASS + o] += p;
        }
    }
}

// ---------------------------------------------------------------------------
extern "C" void kernel_launch(void* const* d_in, const int* in_sizes, int n_in,
                              void* d_out, int out_size, void* d_ws, size_t ws_size,
                              hipStream_t stream)
{
    (void)in_sizes; (void)n_in; (void)out_size; (void)ws_size;
    const int*   word = (const int*)d_in[0];
    const int*   tag  = (const int*)d_in[1];
    const int*   pos1 = (const int*)d_in[2];
    const int*   pos2 = (const int*)d_in[3];
    const float* we   = (const float*)d_in[4];
    const float* te   = (const float*)d_in[5];
    const float* p1e  = (const float*)d_in[6];
    const float* p2e  = (const float*)d_in[7];
    const float* wihf = (const float*)d_in[8];
    const float* whhf = (const float*)d_in[9];
    const float* bihf = (const float*)d_in[10];
    const float* bhhf = (const float*)d_in[11];
    const float* wihb = (const float*)d_in[12];
    const float* whhb = (const float*)d_in[13];
    const float* bihb = (const float*)d_in[14];
    const float* bhhb = (const float*)d_in[15];
    const float* Wc   = (const float*)d_in[16];
    const float* br   = (const float*)d_in[17];

    float* wsp    = (float*)d_ws;
    float* emb    = wsp;                       //  2,048,000
    float* xg     = wsp + 2048000;             // 26,214,400
    float* xf     = xg + 26214400;             //  3,276,800
    float* xb     = xf + 3276800;              //  3,276,800
    float* he     = xb + 3276800;              //     32,768
    float* logits = he + 32768;                //     12,800
    float* att    = logits + 12800;            //     12,800
    int*   e      = (int*)(att + 12800);       //        256 ints
    // post-scan buffers alias the (dead-after-scan) xg region
    float* x    = xg;                          //  3,276,800
    float* u    = xg + 3276800;                //  3,276,800
    float* bb   = xg + 6553600;                //  3,891,200
    float* part = xg + 10444800;               //  3,891,200
    float* s    = xg + 14336000;               //     38,912
    float* v    = s + 38912;                   //     38,912
    float* out  = (float*)d_out;

    emb_gather<<<8000, 256, 0, stream>>>(word, tag, pos1, pos2, we, te, p1e, p2e, emb);
    gemm_xg<<<dim3(8, 100, 2), 256, 0, stream>>>(emb, wihf, bihf, bhhf, wihb, bihb, bhhb, xg);
    lstm_scan_e<<<128, 512, 0, stream>>>(xg, whhf, whhb, xf, xb);
    x_add<<<12800, 256, 0, stream>>>(xf, xb, x);
    find_entity<<<1, 128, 0, stream>>>(pos1, pos2, e);
    compute_he<<<256, 128, 0, stream>>>(x, e, he);
    att_logits<<<100, 128, 0, stream>>>(x, he, logits);
    att_softmax<<<1, 128, 0, stream>>>(logits, att);
    u_squash<<<1600, 128, 0, stream>>>(x, u);
    bb_init<<<15200, 256, 0, stream>>>(br, bb);
    for (int it = 0; it < 3; ++it) {
        s_pass<<<dim3(100, 8), 320, 0, stream>>>(u, Wc, bb, att, part);
        s_reduce<<<152, 256, 0, stream>>>(part, s);
        squash_v<<<10, 256, 0, stream>>>(s, v, out, (it == 2) ? 1 : 0);
        if (it < 2) bb_pass<<<dim3(100, 8), 320, 0, stream>>>(u, Wc, v, bb);
    }
}